// Round 1
// baseline (76.415 us; speedup 1.0000x reference)
//
#include <hip/hip_runtime.h>
#include <math.h>

// Problem constants (match reference)
#define PH 256              // pano H
#define PW 512              // pano W
#define NRAYS (PH * PW)     // 131072
#define NS 300              // samples per ray
#define HV 256
#define WV 256
#define DV 64               // voxel depth (without ground)
#define PI_F 3.14159265358979323846f

// Trilinear fetch from the (ground+voxel) volume, zero padding outside.
// Logical volume: D=65 slices; slice 0 is the constant ground plane (1000.0),
// slices 1..64 map to voxel[0..63].
__device__ __forceinline__ float fetch_vox(const float* __restrict__ vox,
                                           int iz, int iy, int ix) {
    bool valid = ((unsigned)ix < (unsigned)WV) &
                 ((unsigned)iy < (unsigned)HV) &
                 ((unsigned)iz < 65u);
    // clamped address (safe even when invalid / ground)
    int czi = iz < 1 ? 1 : (iz > 64 ? 64 : iz);
    int cy = iy < 0 ? 0 : (iy > HV - 1 ? HV - 1 : iy);
    int cx = ix < 0 ? 0 : (ix > WV - 1 ? WV - 1 : ix);
    float v = vox[((czi - 1) << 16) + (cy << 8) + cx];
    if (iz == 0) v = 1000.0f;
    return valid ? v : 0.0f;
}

__global__ __launch_bounds__(256)
void render_kernel(const float* __restrict__ vox,
                   float* __restrict__ out,        // [NRAYS] raw depth, [NRAYS..2*NRAYS) opacity
                   float* __restrict__ blockMin,
                   float* __restrict__ blockMax) {
    const int r = blockIdx.x * 256 + threadIdx.x;
    const int h = r >> 9;       // / PW
    const int w = r & (PW - 1);

    // ray direction
    const float lat = (0.5f - (float)h * (1.0f / 255.0f)) * PI_F;
    const float lon = (-0.5f - 2.0f * (float)w * (1.0f / 511.0f)) * PI_F;
    float cl, sl, clon, slon;
    __sincosf(lat, &sl, &cl);
    __sincosf(lon, &slon, &clon);
    const float dx = cl * clon;
    const float dy = -cl * slon;
    const float dz = sl;
    const float oz = -1.0f + 2.0f * 2.0f / 128.0f;   // -0.96875

    // Precompute per-step deltas in voxel coordinates.
    // xf = t*dx*128 + 127.5 ; yf = t*dy*128 + 127.5 ; zf = (oz + t*dz)*65 + 64.5
    const float step = 1.0f / (float)NS;
    const float sxd = dx * 128.0f * step;
    const float syd = dy * 128.0f * step;
    const float szd = dz * 65.0f * step;

    const float intv = 64.0f / (float)NS;

    float T = 1.0f;
    float depth = 0.0f;
    float opac = 0.0f;

    float xf = 127.5f;
    float yf = 127.5f;
    float zf = oz * 65.0f + 64.5f;

    for (int i = 1; i <= NS; ++i) {
        xf += sxd; yf += syd; zf += szd;

        float x0f = floorf(xf), y0f = floorf(yf), z0f = floorf(zf);
        float fx = xf - x0f, fy = yf - y0f, fz = zf - z0f;
        int x0 = (int)x0f, y0 = (int)y0f, z0 = (int)z0f;

        float c000 = fetch_vox(vox, z0,     y0,     x0);
        float c001 = fetch_vox(vox, z0,     y0,     x0 + 1);
        float c010 = fetch_vox(vox, z0,     y0 + 1, x0);
        float c011 = fetch_vox(vox, z0,     y0 + 1, x0 + 1);
        float c100 = fetch_vox(vox, z0 + 1, y0,     x0);
        float c101 = fetch_vox(vox, z0 + 1, y0,     x0 + 1);
        float c110 = fetch_vox(vox, z0 + 1, y0 + 1, x0);
        float c111 = fetch_vox(vox, z0 + 1, y0 + 1, x0 + 1);

        float lo = (1.0f - fy) * ((1.0f - fx) * c000 + fx * c001)
                 + fy        * ((1.0f - fx) * c010 + fx * c011);
        float hi = (1.0f - fy) * ((1.0f - fx) * c100 + fx * c101)
                 + fy        * ((1.0f - fx) * c110 + fx * c111);
        float sig = (1.0f - fz) * lo + fz * hi;

        float e = __expf(-sig * intv);
        float prob = T * (1.0f - e);
        depth += prob * ((float)i * step * 64.0f);
        opac += prob;
        T *= e;
        if (T < 1e-6f) break;
    }

    out[r] = depth;             // raw depth (normalized by a later kernel)
    out[NRAYS + r] = opac;

    // block min/max reduction of depth
    __shared__ float smn[256];
    __shared__ float smx[256];
    const int t = threadIdx.x;
    smn[t] = depth;
    smx[t] = depth;
    __syncthreads();
    #pragma unroll
    for (int s = 128; s > 0; s >>= 1) {
        if (t < s) {
            smn[t] = fminf(smn[t], smn[t + s]);
            smx[t] = fmaxf(smx[t], smx[t + s]);
        }
        __syncthreads();
    }
    if (t == 0) {
        blockMin[blockIdx.x] = smn[0];
        blockMax[blockIdx.x] = smx[0];
    }
}

__global__ __launch_bounds__(512)
void reduce_minmax_kernel(const float* __restrict__ blockMin,
                          const float* __restrict__ blockMax,
                          float* __restrict__ mm) {
    __shared__ float smn[512];
    __shared__ float smx[512];
    const int t = threadIdx.x;
    smn[t] = blockMin[t];
    smx[t] = blockMax[t];
    __syncthreads();
    #pragma unroll
    for (int s = 256; s > 0; s >>= 1) {
        if (t < s) {
            smn[t] = fminf(smn[t], smn[t + s]);
            smx[t] = fmaxf(smx[t], smx[t + s]);
        }
        __syncthreads();
    }
    if (t == 0) {
        mm[0] = smn[0];
        mm[1] = smx[0];
    }
}

__global__ __launch_bounds__(256)
void normalize_kernel(float* __restrict__ out, const float* __restrict__ mm) {
    const int r = blockIdx.x * 256 + threadIdx.x;
    const float mn = mm[0];
    const float mx = mm[1];
    out[r] = (out[r] - mn) / (mx - mn);
}

extern "C" void kernel_launch(void* const* d_in, const int* in_sizes, int n_in,
                              void* d_out, int out_size, void* d_ws, size_t ws_size,
                              hipStream_t stream) {
    const float* vox = (const float*)d_in[0];
    float* out = (float*)d_out;
    float* wsf = (float*)d_ws;
    float* blockMin = wsf;          // 512
    float* blockMax = wsf + 512;    // 512
    float* mm = wsf + 1024;         // 2

    const int nblocks = NRAYS / 256;   // 512
    render_kernel<<<nblocks, 256, 0, stream>>>(vox, out, blockMin, blockMax);
    reduce_minmax_kernel<<<1, 512, 0, stream>>>(blockMin, blockMax, mm);
    normalize_kernel<<<nblocks, 256, 0, stream>>>(out, mm);
}

// Round 2
// 55.164 us; speedup vs baseline: 1.3852x; 1.3852x over previous
//
#include <hip/hip_runtime.h>
#include <math.h>

// Problem constants (match reference)
#define PH 256              // pano H
#define PW 512              // pano W
#define NRAYS (PH * PW)     // 131072
#define NS 300              // samples per ray
#define HV 256
#define WV 256
#define DV 64               // voxel depth (without ground)
#define PI_F 3.14159265358979323846f

__device__ __forceinline__ float lerpf(float a, float b, float f) {
    return fmaf(f, b - a, a);
}

// Slow-path trilinear corner fetch from the (ground+voxel) volume, zero
// padding outside. Logical volume: D=65 slices; slice 0 is the constant
// ground plane (1000.0), slices 1..64 map to voxel[0..63].
__device__ __forceinline__ float fetch_vox(const float* __restrict__ vox,
                                           int iz, int iy, int ix) {
    bool valid = ((unsigned)ix < (unsigned)WV) &
                 ((unsigned)iy < (unsigned)HV) &
                 ((unsigned)iz < 65u);
    int czi = iz < 1 ? 1 : (iz > 64 ? 64 : iz);
    int cy = iy < 0 ? 0 : (iy > HV - 1 ? HV - 1 : iy);
    int cx = ix < 0 ? 0 : (ix > WV - 1 ? WV - 1 : ix);
    float v = vox[((czi - 1) << 16) + (cy << 8) + cx];
    if (iz == 0) v = 1000.0f;
    return valid ? v : 0.0f;
}

__global__ __launch_bounds__(256)
void render_kernel(const float* __restrict__ vox,
                   float* __restrict__ out,        // [NRAYS] raw depth, [NRAYS..2*NRAYS) opacity
                   float* __restrict__ blockMin,
                   float* __restrict__ blockMax) {
    const int r = blockIdx.x * 256 + threadIdx.x;
    const int h = r >> 9;       // / PW
    const int w = r & (PW - 1);

    // ray direction
    const float lat = (0.5f - (float)h * (1.0f / 255.0f)) * PI_F;
    const float lon = (-0.5f - 2.0f * (float)w * (1.0f / 511.0f)) * PI_F;
    float cl, sl, clon, slon;
    __sincosf(lat, &sl, &cl);
    __sincosf(lon, &slon, &clon);
    const float dx = cl * clon;
    const float dy = -cl * slon;
    const float dz = sl;
    const float oz = -1.0f + 2.0f * 2.0f / 128.0f;   // -0.96875

    // Per-step deltas in voxel coordinates.
    // xf = t*dx*128 + 127.5 ; yf = t*dy*128 + 127.5 ; zf = (oz + t*dz)*65 + 64.5
    const float step = 1.0f / (float)NS;
    const float sxd = dx * 128.0f * step;
    const float syd = dy * 128.0f * step;
    const float szd = dz * 65.0f * step;

    const float intv = 64.0f / (float)NS;

    float T = 1.0f;
    float depth = 0.0f;
    float opac = 0.0f;
    float dval = 0.0f;

    float xf = 127.5f;
    float yf = 127.5f;
    float zf = oz * 65.0f + 64.5f;

    // cached 2x2x2 corner values; reload only when the cell changes
    int px0 = -100000, py0 = -100000, pz0 = -100000;
    float c000 = 0.f, c001 = 0.f, c010 = 0.f, c011 = 0.f;
    float c100 = 0.f, c101 = 0.f, c110 = 0.f, c111 = 0.f;

    for (int i = 0; i < NS; ++i) {
        xf += sxd; yf += syd; zf += szd; dval += intv;

        float x0f = floorf(xf), y0f = floorf(yf), z0f = floorf(zf);
        float fx = xf - x0f, fy = yf - y0f, fz = zf - z0f;
        int x0 = (int)x0f, y0 = (int)y0f, z0 = (int)z0f;

        if ((x0 != px0) | (y0 != py0) | (z0 != pz0)) {
            px0 = x0; py0 = y0; pz0 = z0;
            bool interior = ((unsigned)x0 < 255u) &
                            ((unsigned)y0 < 255u) &
                            ((unsigned)(z0 - 1) < 63u);
            if (interior) {
                // fast path: 8 loads off one base with immediate offsets
                const float* p = vox + (((z0 - 1) << 16) + (y0 << 8) + x0);
                c000 = p[0];       c001 = p[1];
                c010 = p[256];     c011 = p[257];
                c100 = p[65536];   c101 = p[65537];
                c110 = p[65792];   c111 = p[65793];
            } else {
                c000 = fetch_vox(vox, z0,     y0,     x0);
                c001 = fetch_vox(vox, z0,     y0,     x0 + 1);
                c010 = fetch_vox(vox, z0,     y0 + 1, x0);
                c011 = fetch_vox(vox, z0,     y0 + 1, x0 + 1);
                c100 = fetch_vox(vox, z0 + 1, y0,     x0);
                c101 = fetch_vox(vox, z0 + 1, y0,     x0 + 1);
                c110 = fetch_vox(vox, z0 + 1, y0 + 1, x0);
                c111 = fetch_vox(vox, z0 + 1, y0 + 1, x0 + 1);
            }
        }

        float l00 = lerpf(c000, c001, fx);
        float l01 = lerpf(c010, c011, fx);
        float l10 = lerpf(c100, c101, fx);
        float l11 = lerpf(c110, c111, fx);
        float lo  = lerpf(l00, l01, fy);
        float hi  = lerpf(l10, l11, fy);
        float sig = lerpf(lo, hi, fz);

        float e = __expf(-sig * intv);
        float prob = T - T * e;            // T * (1 - e)
        depth = fmaf(prob, dval, depth);
        opac += prob;
        T *= e;
        if (T < 1e-6f) break;
    }

    out[r] = depth;             // raw depth (normalized by a later kernel)
    out[NRAYS + r] = opac;

    // block min/max reduction of depth
    __shared__ float smn[256];
    __shared__ float smx[256];
    const int t = threadIdx.x;
    smn[t] = depth;
    smx[t] = depth;
    __syncthreads();
    #pragma unroll
    for (int s = 128; s > 0; s >>= 1) {
        if (t < s) {
            smn[t] = fminf(smn[t], smn[t + s]);
            smx[t] = fmaxf(smx[t], smx[t + s]);
        }
        __syncthreads();
    }
    if (t == 0) {
        blockMin[blockIdx.x] = smn[0];
        blockMax[blockIdx.x] = smx[0];
    }
}

__global__ __launch_bounds__(512)
void reduce_minmax_kernel(const float* __restrict__ blockMin,
                          const float* __restrict__ blockMax,
                          float* __restrict__ mm) {
    __shared__ float smn[512];
    __shared__ float smx[512];
    const int t = threadIdx.x;
    smn[t] = blockMin[t];
    smx[t] = blockMax[t];
    __syncthreads();
    #pragma unroll
    for (int s = 256; s > 0; s >>= 1) {
        if (t < s) {
            smn[t] = fminf(smn[t], smn[t + s]);
            smx[t] = fmaxf(smx[t], smx[t + s]);
        }
        __syncthreads();
    }
    if (t == 0) {
        mm[0] = smn[0];
        mm[1] = smx[0];
    }
}

__global__ __launch_bounds__(256)
void normalize_kernel(float* __restrict__ out, const float* __restrict__ mm) {
    const int r = blockIdx.x * 256 + threadIdx.x;
    const float mn = mm[0];
    const float mx = mm[1];
    out[r] = (out[r] - mn) / (mx - mn);
}

extern "C" void kernel_launch(void* const* d_in, const int* in_sizes, int n_in,
                              void* d_out, int out_size, void* d_ws, size_t ws_size,
                              hipStream_t stream) {
    const float* vox = (const float*)d_in[0];
    float* out = (float*)d_out;
    float* wsf = (float*)d_ws;
    float* blockMin = wsf;          // 512
    float* blockMax = wsf + 512;    // 512
    float* mm = wsf + 1024;         // 2

    const int nblocks = NRAYS / 256;   // 512
    render_kernel<<<nblocks, 256, 0, stream>>>(vox, out, blockMin, blockMax);
    reduce_minmax_kernel<<<1, 512, 0, stream>>>(blockMin, blockMax, mm);
    normalize_kernel<<<nblocks, 256, 0, stream>>>(out, mm);
}